// Round 8
// baseline (351.673 us; speedup 1.0000x reference)
//
#include <hip/hip_runtime.h>
#include <hip/hip_bf16.h>
#include <math.h>

#define HID 256
typedef __attribute__((ext_vector_type(8))) short s16x8;
typedef __attribute__((ext_vector_type(4))) float f32x4;

__device__ __forceinline__ ushort f2bf(float f){
    uint u = __float_as_uint(f);
    u += 0x7FFF + ((u>>16)&1);
    return (ushort)(u>>16);
}
__device__ __forceinline__ float bf2f(ushort b){
    return __uint_as_float(((uint)b)<<16);
}
__device__ __forceinline__ float4 bf4_to_f4(ushort4 u){
    return make_float4(bf2f(u.x), bf2f(u.y), bf2f(u.z), bf2f(u.w));
}

// gelu tanh-approx, tanh via fast exp: tanh(u) = 1 - 2/(1+exp(2u))
__device__ __forceinline__ float gelu_tanh(float x){
    float u = 0.7978845608028654f*(x + 0.044715f*x*x*x);
    float t = 1.0f - 2.0f/(1.0f + __expf(2.0f*u));
    return 0.5f*x*(1.0f+t);
}

__global__ void k_count(const int* __restrict__ dst, int* __restrict__ cnt, int E){
    int e = blockIdx.x*blockDim.x + threadIdx.x;
    if(e<E) atomicAdd(&cnt[dst[e]], 1);
}

__global__ __launch_bounds__(256) void k_scan1(const int* __restrict__ cnt,
    int* __restrict__ tsum, int* __restrict__ bsum, int N){
    __shared__ int sm[256];
    int t = threadIdx.x, b = blockIdx.x;
    int base = b*1024 + t*4;
    int c0=0,c1=0,c2=0,c3=0;
    if(base+3 < N){
        int4 c = *reinterpret_cast<const int4*>(&cnt[base]);
        c0=c.x; c1=c.y; c2=c.z; c3=c.w;
    }else{
        if(base  <N) c0=cnt[base];
        if(base+1<N) c1=cnt[base+1];
        if(base+2<N) c2=cnt[base+2];
        if(base+3<N) c3=cnt[base+3];
    }
    int s = c0+c1+c2+c3;
    sm[t]=s; __syncthreads();
    for(int off=1; off<256; off<<=1){
        int v = sm[t];
        int a = (t>=off)? sm[t-off] : 0;
        __syncthreads();
        sm[t] = v+a;
        __syncthreads();
    }
    tsum[b*256+t] = sm[t]-s;
    if(t==255) bsum[b] = sm[255];
}

// scan3: each block sums bsum[0..b-1] itself (B<=20), writes indptr/cursor/dinv
__global__ __launch_bounds__(256) void k_scan3(const int* __restrict__ cnt,
    const int* __restrict__ tsum, const int* __restrict__ bsum,
    int* __restrict__ indptr, int* __restrict__ cursor, float* __restrict__ dinv,
    int N, int B){
    __shared__ int sboff;
    int t = threadIdx.x, b = blockIdx.x;
    if(t==0){
        int run=0, tot=0;
        for(int i=0;i<B;i++){ int v=bsum[i]; if(i<b) run+=v; tot+=v; }
        sboff=run;
        if(b==0) indptr[N]=tot;
    }
    __syncthreads();
    int base = b*1024 + t*4;
    int run = sboff + tsum[b*256+t];
    #pragma unroll
    for(int i=0;i<4;i++){
        int idx = base+i;
        if(idx<N){
            int c = cnt[idx];
            indptr[idx]=run; cursor[idx]=run;
            dinv[idx] = rsqrtf((float)(c+1));
            run += c;
        }
    }
}

__global__ void k_fill(const int* __restrict__ src, const int* __restrict__ dst,
    int* __restrict__ cursor, int* __restrict__ csr, int E){
    int e = blockIdx.x*blockDim.x + threadIdx.x;
    if(e<E){
        int pos = atomicAdd(&cursor[dst[e]], 1);
        csr[pos] = src[e];
    }
}

// combined weight convert: W_in (128x256) + Wc (6x256x256), fragment-shuffled bf16
// layout: Wb[((kb*256+n)*4+hi)*8+ii], k = kb*32+hi*8+ii
__global__ void k_cvt_w(const float* __restrict__ Win, const float* __restrict__ Wc,
    ushort* __restrict__ wbin, ushort* __restrict__ wbc){
    int i = blockIdx.x*blockDim.x + threadIdx.x;
    if(i < 32768){
        int k = i >> 8, n = i & 255;
        int kb = k>>5, hi=(k>>3)&3, ii=k&7;
        wbin[((kb*256+n)*4+hi)*8 + ii] = f2bf(Win[i]);
    }else if(i < 32768 + 6*65536){
        int j = i - 32768;
        int l = j >> 16;
        int k = (j>>8)&255, n = j&255;
        int kb = k>>5, hi=(k>>3)&3, ii=k&7;
        wbc[l*65536 + ((kb*256+n)*4+hi)*8 + ii] = f2bf(Wc[j]);
    }
}

// epilogue for input kernel (16-row tile, 4 waves)
__device__ __forceinline__ void epilogue_in(f32x4 (&acc)[4],
    const float* __restrict__ bp, const float* __restrict__ gp, const float* __restrict__ bep,
    ushort* __restrict__ h0b, ushort* __restrict__ xb,
    int row0, int wc, int lr, int hi, int N,
    float (*sm1)[4], float (*sm2)[4])
{
    float bcv[4], gcv[4], bev[4];
    #pragma unroll
    for(int nf=0;nf<4;nf++){
        int col = wc*64 + nf*16 + lr;
        bcv[nf]=bp[col]; gcv[nf]=gp[col]; bev[nf]=bep[col];
    }
    #pragma unroll
    for(int r=0;r<4;r++){
        float ls1=0.f, ls2=0.f;
        #pragma unroll
        for(int nf=0;nf<4;nf++){
            float t = gelu_tanh(acc[nf][r] + bcv[nf]);
            acc[nf][r] = t;
            ls1 += t; ls2 += t*t;
        }
        #pragma unroll
        for(int off=1; off<16; off<<=1){
            ls1 += __shfl_xor(ls1, off, 64);
            ls2 += __shfl_xor(ls2, off, 64);
        }
        if(lr==0){
            int row = hi*4 + r;
            sm1[row][wc]=ls1; sm2[row][wc]=ls2;
        }
    }
    __syncthreads();
    #pragma unroll
    for(int r=0;r<4;r++){
        int row = hi*4 + r;
        int grow = row0 + row;
        if(grow >= N) continue;
        float S1 = sm1[row][0]+sm1[row][1]+sm1[row][2]+sm1[row][3];
        float S2 = sm2[row][0]+sm2[row][1]+sm2[row][2]+sm2[row][3];
        float mu = S1*(1.0f/256.0f);
        float var = fmaxf(S2*(1.0f/256.0f) - mu*mu, 0.0f);
        float rs = rsqrtf(var + 1e-5f);
        #pragma unroll
        for(int nf=0;nf<4;nf++){
            int col = wc*64 + nf*16 + lr;
            size_t idx = (size_t)grow*HID + col;
            float o = (acc[nf][r]-mu)*rs*gcv[nf] + bev[nf];
            ushort ob = f2bf(o);
            h0b[idx] = ob;
            xb[idx] = ob;
        }
    }
}

// input block: 16-row tiles, reads fp32 X[N][128] directly, converts fragments in-reg
__global__ __launch_bounds__(256) void k_gemm_in(const float* __restrict__ X,
    const ushort* __restrict__ Wb,
    const float* __restrict__ bp, const float* __restrict__ gp, const float* __restrict__ bep,
    ushort* __restrict__ h0b, ushort* __restrict__ xb, int N)
{
    const int lane = threadIdx.x & 63;
    const int wc = threadIdx.x >> 6;
    const int lr = lane & 15;
    const int hi = lane >> 4;
    const int row0 = blockIdx.x*16;
    __shared__ float sm1[16][4];
    __shared__ float sm2[16][4];

    f32x4 acc[4];
    #pragma unroll
    for(int n=0;n<4;n++){ acc[n].x=0.f; acc[n].y=0.f; acc[n].z=0.f; acc[n].w=0.f; }

    int r0 = row0 + lr; if(r0 >= N) r0 = N-1;
    const float* xp0 = X + (size_t)r0*128 + hi*8;
    const ushort* bpp = Wb + (wc*64 + lr)*32 + hi*8;

    #pragma unroll
    for(int kb=0; kb<4; kb++){
        float4 p0a = *reinterpret_cast<const float4*>(xp0 + kb*32);
        float4 p0b = *reinterpret_cast<const float4*>(xp0 + kb*32 + 4);
        s16x8 a0;
        a0[0]=(short)f2bf(p0a.x); a0[1]=(short)f2bf(p0a.y); a0[2]=(short)f2bf(p0a.z); a0[3]=(short)f2bf(p0a.w);
        a0[4]=(short)f2bf(p0b.x); a0[5]=(short)f2bf(p0b.y); a0[6]=(short)f2bf(p0b.z); a0[7]=(short)f2bf(p0b.w);
        #pragma unroll
        for(int nf=0;nf<4;nf++){
            s16x8 b = *reinterpret_cast<const s16x8*>(bpp + kb*8192 + nf*512);
            acc[nf] = __builtin_amdgcn_mfma_f32_16x16x32_bf16(a0, b, acc[nf], 0,0,0);
        }
    }
    epilogue_in(acc, bp, gp, bep, h0b, xb, row0, wc, lr, hi, N, sm1, sm2);
}

// Fused conv layer: 1024-thread block = 16 waves, 16-row tile.
// Phase 1 (gather): wave w aggregates node row0+w (1 node/wave, 8-deep MLP) -> swizzled LDS A-tile
// Phase 2 (GEMM):   wave (kq,wc) kq=w>>3, wc=w&7: K-half kq*128, cols wc*32..+31; partials -> LDS
// Phase 3 (epi):    wave w does full LN row row0+w; blend; write xbB (or fout fp32 for last layer)
// MODE: 1=conv (write xbB bf16), 2=last (write fout fp32)
template<int MODE>
__global__ __launch_bounds__(1024, 8) void k_layer(const ushort* __restrict__ xbA,
    const ushort* __restrict__ Wb,
    const int* __restrict__ indptr, const int* __restrict__ csr,
    const float* __restrict__ dinv,
    const float* __restrict__ bp, const float* __restrict__ gp, const float* __restrict__ bep,
    const ushort* __restrict__ h0b, ushort* __restrict__ xbB, float* __restrict__ fout, int N)
{
    __shared__ ushort als[16*256];     // 8 KB swizzled A tile (bf16)
    __shared__ float yls[2*16*256];    // 32 KB: two K-half partial Y tiles (f32)
    const int tid = threadIdx.x;
    const int w = tid >> 6;
    const int lane = tid & 63;
    const int row0 = blockIdx.x*16;
    char* ab = (char*)als;

    // ---- phase 1: gather node row0+w ----
    {
        int n = row0 + w; if(n >= N) n = N-1;
        float dn = dinv[n];
        const ushort4* X4 = reinterpret_cast<const ushort4*>(xbA);
        float4 sv = bf4_to_f4(X4[(size_t)n*64 + lane]);
        float4 acc = make_float4(dn*sv.x, dn*sv.y, dn*sv.z, dn*sv.w);
        int e0 = indptr[n], e1 = indptr[n+1];
        int e = e0;
        for(; e+8<=e1; e+=8){
            int idx[8];
            #pragma unroll
            for(int q=0;q<8;q++) idx[q]=csr[e+q];
            float4 v[8]; float dv[8];
            #pragma unroll
            for(int q=0;q<8;q++){ v[q]=bf4_to_f4(X4[(size_t)idx[q]*64+lane]); dv[q]=dinv[idx[q]]; }
            #pragma unroll
            for(int q=0;q<8;q++){
                acc.x = fmaf(dv[q],v[q].x,acc.x);
                acc.y = fmaf(dv[q],v[q].y,acc.y);
                acc.z = fmaf(dv[q],v[q].z,acc.z);
                acc.w = fmaf(dv[q],v[q].w,acc.w);
            }
        }
        for(; e<e1; e++){
            int s = csr[e];
            float4 v = bf4_to_f4(X4[(size_t)s*64+lane]); float d=dinv[s];
            acc.x = fmaf(d,v.x,acc.x); acc.y = fmaf(d,v.y,acc.y);
            acc.z = fmaf(d,v.z,acc.z); acc.w = fmaf(d,v.w,acc.w);
        }
        ushort4 o; o.x=f2bf(dn*acc.x); o.y=f2bf(dn*acc.y); o.z=f2bf(dn*acc.z); o.w=f2bf(dn*acc.w);
        *reinterpret_cast<ushort4*>(ab + w*512 + ((lane*8) ^ ((w&7)<<4))) = o;
    }
    __syncthreads();

    // ---- phase 2: GEMM, wave (kq,wc): K range kq*128..+127, cols wc*32..+31 ----
    {
        const int kq = w >> 3, wc = w & 7;
        const int lr = lane & 15, hi = lane >> 4;
        f32x4 acc2[2];
        #pragma unroll
        for(int nf=0;nf<2;nf++){ acc2[nf].x=0.f; acc2[nf].y=0.f; acc2[nf].z=0.f; acc2[nf].w=0.f; }
        const ushort* bpp = Wb + (wc*32 + lr)*32 + hi*8;
        const int sws = (lr&7)<<4;
        #pragma unroll
        for(int kbl=0; kbl<4; kbl++){
            int kb = kq*4 + kbl;
            int cb = kb*64 + hi*16;
            s16x8 a = *reinterpret_cast<const s16x8*>(ab + lr*512 + (cb ^ sws));
            s16x8 b0 = *reinterpret_cast<const s16x8*>(bpp + kb*8192);
            s16x8 b1 = *reinterpret_cast<const s16x8*>(bpp + kb*8192 + 512);
            acc2[0] = __builtin_amdgcn_mfma_f32_16x16x32_bf16(a, b0, acc2[0], 0,0,0);
            acc2[1] = __builtin_amdgcn_mfma_f32_16x16x32_bf16(a, b1, acc2[1], 0,0,0);
        }
        // stage partials: C layout col=lr, row=hi*4+r
        float* yb_ = yls + kq*4096;
        #pragma unroll
        for(int nf=0;nf<2;nf++){
            #pragma unroll
            for(int r=0;r<4;r++)
                yb_[(hi*4+r)*256 + wc*32 + nf*16 + lr] = acc2[nf][r];
        }
    }
    __syncthreads();

    // ---- phase 3: epilogue, wave w -> row row0+w ----
    {
        int grow = row0 + w;
        if(grow < N){
            float4 t0 = *reinterpret_cast<const float4*>(&yls[w*256 + lane*4]);
            float4 t1 = *reinterpret_cast<const float4*>(&yls[4096 + w*256 + lane*4]);
            float4 bb4 = *reinterpret_cast<const float4*>(&bp[lane*4]);
            float4 t;
            t.x = gelu_tanh(t0.x+t1.x+bb4.x);
            t.y = gelu_tanh(t0.y+t1.y+bb4.y);
            t.z = gelu_tanh(t0.z+t1.z+bb4.z);
            t.w = gelu_tanh(t0.w+t1.w+bb4.w);
            float s1 = t.x+t.y+t.z+t.w;
            float s2 = t.x*t.x+t.y*t.y+t.z*t.z+t.w*t.w;
            #pragma unroll
            for(int off=32; off>0; off>>=1){
                s1 += __shfl_xor(s1, off, 64);
                s2 += __shfl_xor(s2, off, 64);
            }
            float mu = s1*(1.0f/256.0f);
            float var = fmaxf(s2*(1.0f/256.0f) - mu*mu, 0.0f);
            float rs = rsqrtf(var + 1e-5f);
            float4 gg = *reinterpret_cast<const float4*>(&gp[lane*4]);
            float4 be4 = *reinterpret_cast<const float4*>(&bep[lane*4]);
            float4 o;
            o.x = (t.x-mu)*rs*gg.x + be4.x;
            o.y = (t.y-mu)*rs*gg.y + be4.y;
            o.z = (t.z-mu)*rs*gg.z + be4.z;
            o.w = (t.w-mu)*rs*gg.w + be4.w;
            float4 h = bf4_to_f4(reinterpret_cast<const ushort4*>(h0b)[(size_t)grow*64+lane]);
            float4 xc = bf4_to_f4(reinterpret_cast<const ushort4*>(xbA)[(size_t)grow*64+lane]);
            xc.x += 0.9f*o.x + 0.1f*h.x;
            xc.y += 0.9f*o.y + 0.1f*h.y;
            xc.z += 0.9f*o.z + 0.1f*h.z;
            xc.w += 0.9f*o.w + 0.1f*h.w;
            if(MODE==1){
                ushort4 ob; ob.x=f2bf(xc.x); ob.y=f2bf(xc.y); ob.z=f2bf(xc.z); ob.w=f2bf(xc.w);
                reinterpret_cast<ushort4*>(xbB)[(size_t)grow*64+lane] = ob;
            }else{
                reinterpret_cast<float4*>(fout)[(size_t)grow*64+lane] = xc;
            }
        }
    }
}

extern "C" void kernel_launch(void* const* d_in, const int* in_sizes, int n_in,
                              void* d_out, int out_size, void* d_ws, size_t ws_size,
                              hipStream_t stream){
    const float* x     = (const float*)d_in[0];
    const int*   ei    = (const int*)d_in[1];
    const float* W_in  = (const float*)d_in[2];
    const float* b_in  = (const float*)d_in[3];
    const float* g_in  = (const float*)d_in[4];
    const float* be_in = (const float*)d_in[5];
    const float* Wc    = (const float*)d_in[6];
    const float* bc    = (const float*)d_in[7];
    const float* gc    = (const float*)d_in[8];
    const float* bec   = (const float*)d_in[9];
    const int N = in_sizes[0]/128;
    const int E = in_sizes[1]/2;
    const int* src = ei;
    const int* dst = ei + E;
    float* fout = (float*)d_out;
    const int B = (N+1023)/1024;

    char* w = (char*)d_ws;
    ushort* xb0  = (ushort*)w; w += (size_t)N*HID*2;
    ushort* xb1  = (ushort*)w; w += (size_t)N*HID*2;
    ushort* h0b  = (ushort*)w; w += (size_t)N*HID*2;
    ushort* wbin = (ushort*)w; w += (size_t)128*256*2;
    ushort* wbc  = (ushort*)w; w += (size_t)6*65536*2;
    float* dinv  = (float*)w;  w += (size_t)N*4;
    int* cnt     = (int*)w;    w += (size_t)N*4;
    int* cursor  = (int*)w;    w += (size_t)N*4;
    int* csr     = (int*)w;    w += (size_t)E*4;
    int* indptr  = (int*)w;    w += (size_t)(N+1)*4;
    int* tsum    = (int*)w;    w += (size_t)B*256*4;
    int* bsum    = (int*)w;    w += (size_t)B*4;

    (void)hipMemsetAsync(cnt, 0, (size_t)N*4, stream);
    k_cvt_w<<<(32768+6*65536+255)/256,256,0,stream>>>(W_in, Wc, wbin, wbc);
    k_count<<<(E+255)/256,256,0,stream>>>(dst,cnt,E);
    k_scan1<<<B,256,0,stream>>>(cnt, tsum, bsum, N);
    k_scan3<<<B,256,0,stream>>>(cnt, tsum, bsum, indptr, cursor, dinv, N, B);
    k_fill<<<(E+255)/256,256,0,stream>>>(src,dst,cursor,csr,E);

    const int GB = (N+15)/16;
    k_gemm_in<<<GB,256,0,stream>>>(x, wbin, b_in, g_in, be_in, h0b, xb0, N);
    ushort* xsA = xb0;
    ushort* xsB = xb1;
    for(int l=0;l<6;l++){
        if(l<5){
            k_layer<1><<<GB,1024,0,stream>>>(xsA, wbc+(size_t)l*65536, indptr, csr, dinv,
                bc+(size_t)l*HID, gc+(size_t)l*HID, bec+(size_t)l*HID,
                h0b, xsB, nullptr, N);
        }else{
            k_layer<2><<<GB,1024,0,stream>>>(xsA, wbc+(size_t)l*65536, indptr, csr, dinv,
                bc+(size_t)l*HID, gc+(size_t)l*HID, bec+(size_t)l*HID,
                h0b, nullptr, fout, N);
        }
        ushort* t = xsA; xsA = xsB; xsB = t;
    }
}

// Round 10
// 326.734 us; speedup vs baseline: 1.0763x; 1.0763x over previous
//
#include <hip/hip_runtime.h>
#include <hip/hip_bf16.h>
#include <math.h>

#define HID 256
typedef __attribute__((ext_vector_type(8))) short s16x8;
typedef __attribute__((ext_vector_type(8))) ushort u16x8;
typedef __attribute__((ext_vector_type(4))) float f32x4;

__device__ __forceinline__ ushort f2bf(float f){
    uint u = __float_as_uint(f);
    u += 0x7FFF + ((u>>16)&1);
    return (ushort)(u>>16);
}
__device__ __forceinline__ float bf2f(ushort b){
    return __uint_as_float(((uint)b)<<16);
}
__device__ __forceinline__ float4 bf4_to_f4(ushort4 u){
    return make_float4(bf2f(u.x), bf2f(u.y), bf2f(u.z), bf2f(u.w));
}

// gelu tanh-approx, tanh via fast exp: tanh(u) = 1 - 2/(1+exp(2u))
__device__ __forceinline__ float gelu_tanh(float x){
    float u = 0.7978845608028654f*(x + 0.044715f*x*x*x);
    float t = 1.0f - 2.0f/(1.0f + __expf(2.0f*u));
    return 0.5f*x*(1.0f+t);
}

// merged: weight convert (blocks < CVTB) + degree count (rest)
#define CVTB 1664
__global__ void k_cvt_count(const float* __restrict__ Win, const float* __restrict__ Wc,
    ushort* __restrict__ wbin, ushort* __restrict__ wbc,
    const int* __restrict__ dst, int* __restrict__ cnt, int E){
    int b = blockIdx.x;
    if(b < CVTB){
        int i = b*256 + threadIdx.x;
        if(i < 32768){
            int k = i >> 8, n = i & 255;
            int kb = k>>5, hi=(k>>3)&3, ii=k&7;
            wbin[((kb*256+n)*4+hi)*8 + ii] = f2bf(Win[i]);
        }else{
            int j = i - 32768;
            int l = j >> 16;
            int k = (j>>8)&255, n = j&255;
            int kb = k>>5, hi=(k>>3)&3, ii=k&7;
            wbc[l*65536 + ((kb*256+n)*4+hi)*8 + ii] = f2bf(Wc[j]);
        }
    }else{
        int e = (b-CVTB)*256 + threadIdx.x;
        if(e<E) atomicAdd(&cnt[dst[e]], 1);
    }
}

__global__ __launch_bounds__(256) void k_scan1(const int* __restrict__ cnt,
    int* __restrict__ tsum, int* __restrict__ bsum, int N){
    __shared__ int sm[256];
    int t = threadIdx.x, b = blockIdx.x;
    int base = b*1024 + t*4;
    int c0=0,c1=0,c2=0,c3=0;
    if(base+3 < N){
        int4 c = *reinterpret_cast<const int4*>(&cnt[base]);
        c0=c.x; c1=c.y; c2=c.z; c3=c.w;
    }else{
        if(base  <N) c0=cnt[base];
        if(base+1<N) c1=cnt[base+1];
        if(base+2<N) c2=cnt[base+2];
        if(base+3<N) c3=cnt[base+3];
    }
    int s = c0+c1+c2+c3;
    sm[t]=s; __syncthreads();
    for(int off=1; off<256; off<<=1){
        int v = sm[t];
        int a = (t>=off)? sm[t-off] : 0;
        __syncthreads();
        sm[t] = v+a;
        __syncthreads();
    }
    tsum[b*256+t] = sm[t]-s;
    if(t==255) bsum[b] = sm[255];
}

// scan3: each block sums bsum[0..b-1] itself (B<=20), writes indptr/cursor/dinv
__global__ __launch_bounds__(256) void k_scan3(const int* __restrict__ cnt,
    const int* __restrict__ tsum, const int* __restrict__ bsum,
    int* __restrict__ indptr, int* __restrict__ cursor, float* __restrict__ dinv,
    int N, int B){
    __shared__ int sboff;
    int t = threadIdx.x, b = blockIdx.x;
    if(t==0){
        int run=0, tot=0;
        for(int i=0;i<B;i++){ int v=bsum[i]; if(i<b) run+=v; tot+=v; }
        sboff=run;
        if(b==0) indptr[N]=tot;
    }
    __syncthreads();
    int base = b*1024 + t*4;
    int run = sboff + tsum[b*256+t];
    #pragma unroll
    for(int i=0;i<4;i++){
        int idx = base+i;
        if(idx<N){
            int c = cnt[idx];
            indptr[idx]=run; cursor[idx]=run;
            dinv[idx] = rsqrtf((float)(c+1));
            run += c;
        }
    }
}

__global__ void k_fill(const int* __restrict__ src, const int* __restrict__ dst,
    int* __restrict__ cursor, int* __restrict__ csr, int E){
    int e = blockIdx.x*blockDim.x + threadIdx.x;
    if(e<E){
        int pos = atomicAdd(&cursor[dst[e]], 1);
        csr[pos] = src[e];
    }
}

// pair-gather: 2 edges per wave-instruction. lane<32 -> even edge, lane>=32 -> odd edge,
// each half covers the full 256-col row with 8 bf16 (16B) per lane.
// yb[n] = bf16( dinv[n] * (dinv[n]*x[n] + sum_e dinv[src]*x[src]) )
__global__ __launch_bounds__(256) void k_agg(const ushort* __restrict__ xb,
    const int* __restrict__ indptr, const int* __restrict__ csr,
    const float* __restrict__ dinv, ushort* __restrict__ yb, int N)
{
    int wave = threadIdx.x>>6, lane = threadIdx.x&63;
    int n = blockIdx.x*4 + wave;
    if(n>=N) return;
    const u16x8* X8 = reinterpret_cast<const u16x8*>(xb);
    const int half = lane >> 5;
    const int l = lane & 31;
    float dn = dinv[n];
    float acc[8];
    {   // self loop: half 0 carries it with weight dn (outer dn applied at store)
        u16x8 v = X8[(size_t)n*32 + l];
        float w0 = (half==0)? dn : 0.f;
        #pragma unroll
        for(int j=0;j<8;j++) acc[j] = w0 * bf2f(v[j]);
    }
    int e0 = indptr[n], e1 = indptr[n+1];
    int e = e0;
    for(; e+8<=e1; e+=8){   // 4 pairs = 8 edges in flight
        int is[4];
        #pragma unroll
        for(int q=0;q<4;q++) is[q] = csr[e + q*2 + half];
        u16x8 vs[4];
        #pragma unroll
        for(int q=0;q<4;q++) vs[q] = X8[(size_t)is[q]*32 + l];
        float ds[4];
        #pragma unroll
        for(int q=0;q<4;q++) ds[q] = dinv[is[q]];
        #pragma unroll
        for(int q=0;q<4;q++){
            #pragma unroll
            for(int j=0;j<8;j++) acc[j] = fmaf(ds[q], bf2f(vs[q][j]), acc[j]);
        }
    }
    for(; e+2<=e1; e+=2){
        int i = csr[e + half];
        u16x8 v = X8[(size_t)i*32 + l];
        float d = dinv[i];
        #pragma unroll
        for(int j=0;j<8;j++) acc[j] = fmaf(d, bf2f(v[j]), acc[j]);
    }
    if(e<e1){   // odd tail: half 0 only (half 1 weight 0)
        int i = csr[e];
        u16x8 v = X8[(size_t)i*32 + l];
        float d = (half==0)? dinv[i] : 0.f;
        #pragma unroll
        for(int j=0;j<8;j++) acc[j] = fmaf(d, bf2f(v[j]), acc[j]);
    }
    #pragma unroll
    for(int j=0;j<8;j++) acc[j] += __shfl_xor(acc[j], 32, 64);
    if(half==0){
        u16x8 o;
        #pragma unroll
        for(int j=0;j<8;j++) o[j] = f2bf(dn*acc[j]);
        reinterpret_cast<u16x8*>(yb)[(size_t)n*32 + l] = o;
    }
}

// epilogue for 16-row tiles. MODE: 0=INPUT (h0b=xb=o), 1=CONV (xb += 0.9o+0.1h0),
// 2=LAST (fout = xb + 0.9o + 0.1h0, fp32)
template<int MODE>
__device__ __forceinline__ void epilogue16(f32x4 (&acc)[4],
    const float* __restrict__ bp, const float* __restrict__ gp, const float* __restrict__ bep,
    ushort* __restrict__ h0b, ushort* __restrict__ xb, float* __restrict__ fout,
    int row0, int wc, int lr, int hi, int N,
    float (*sm1)[4], float (*sm2)[4])
{
    float bcv[4], gcv[4], bev[4];
    #pragma unroll
    for(int nf=0;nf<4;nf++){
        int col = wc*64 + nf*16 + lr;
        bcv[nf]=bp[col]; gcv[nf]=gp[col]; bev[nf]=bep[col];
    }
    #pragma unroll
    for(int r=0;r<4;r++){
        float ls1=0.f, ls2=0.f;
        #pragma unroll
        for(int nf=0;nf<4;nf++){
            float t = gelu_tanh(acc[nf][r] + bcv[nf]);
            acc[nf][r] = t;
            ls1 += t; ls2 += t*t;
        }
        #pragma unroll
        for(int off=1; off<16; off<<=1){
            ls1 += __shfl_xor(ls1, off, 64);
            ls2 += __shfl_xor(ls2, off, 64);
        }
        if(lr==0){
            int row = hi*4 + r;
            sm1[row][wc]=ls1; sm2[row][wc]=ls2;
        }
    }
    __syncthreads();
    #pragma unroll
    for(int r=0;r<4;r++){
        int row = hi*4 + r;
        int grow = row0 + row;
        if(grow >= N) continue;
        float S1 = sm1[row][0]+sm1[row][1]+sm1[row][2]+sm1[row][3];
        float S2 = sm2[row][0]+sm2[row][1]+sm2[row][2]+sm2[row][3];
        float mu = S1*(1.0f/256.0f);
        float var = fmaxf(S2*(1.0f/256.0f) - mu*mu, 0.0f);
        float rs = rsqrtf(var + 1e-5f);
        #pragma unroll
        for(int nf=0;nf<4;nf++){
            int col = wc*64 + nf*16 + lr;
            size_t idx = (size_t)grow*HID + col;
            float o = (acc[nf][r]-mu)*rs*gcv[nf] + bev[nf];
            if(MODE==0){
                ushort ob = f2bf(o);
                h0b[idx] = ob;
                xb[idx] = ob;
            }else{
                float xc = bf2f(xb[idx]) + 0.9f*o + 0.1f*bf2f(h0b[idx]);
                if(MODE==1) xb[idx] = f2bf(xc);
                else        fout[idx] = xc;
            }
        }
    }
}

// input block: 16-row tiles, reads fp32 X[N][128] directly, converts fragments in-reg
__global__ __launch_bounds__(256) void k_gemm_in(const float* __restrict__ X,
    const ushort* __restrict__ Wb,
    const float* __restrict__ bp, const float* __restrict__ gp, const float* __restrict__ bep,
    ushort* __restrict__ h0b, ushort* __restrict__ xb, int N)
{
    const int lane = threadIdx.x & 63;
    const int wc = threadIdx.x >> 6;
    const int lr = lane & 15;
    const int hi = lane >> 4;
    const int row0 = blockIdx.x*16;
    __shared__ float sm1[16][4];
    __shared__ float sm2[16][4];

    f32x4 acc[4];
    #pragma unroll
    for(int n=0;n<4;n++){ acc[n].x=0.f; acc[n].y=0.f; acc[n].z=0.f; acc[n].w=0.f; }

    int r0 = row0 + lr; if(r0 >= N) r0 = N-1;
    const float* xp0 = X + (size_t)r0*128 + hi*8;
    const ushort* bpp = Wb + (wc*64 + lr)*32 + hi*8;

    #pragma unroll
    for(int kb=0; kb<4; kb++){
        float4 p0a = *reinterpret_cast<const float4*>(xp0 + kb*32);
        float4 p0b = *reinterpret_cast<const float4*>(xp0 + kb*32 + 4);
        s16x8 a0;
        a0[0]=(short)f2bf(p0a.x); a0[1]=(short)f2bf(p0a.y); a0[2]=(short)f2bf(p0a.z); a0[3]=(short)f2bf(p0a.w);
        a0[4]=(short)f2bf(p0b.x); a0[5]=(short)f2bf(p0b.y); a0[6]=(short)f2bf(p0b.z); a0[7]=(short)f2bf(p0b.w);
        #pragma unroll
        for(int nf=0;nf<4;nf++){
            s16x8 b = *reinterpret_cast<const s16x8*>(bpp + kb*8192 + nf*512);
            acc[nf] = __builtin_amdgcn_mfma_f32_16x16x32_bf16(a0, b, acc[nf], 0,0,0);
        }
    }
    epilogue16<0>(acc, bp, gp, bep, h0b, xb, nullptr, row0, wc, lr, hi, N, sm1, sm2);
}

// conv GEMM: 16-row tiles, A = yb (aggregated bf16), fused bias/gelu/LN/blend
template<int MODE>
__global__ __launch_bounds__(256) void k_gemm_fused(const ushort* __restrict__ A,
    const ushort* __restrict__ Wb,
    const float* __restrict__ bp, const float* __restrict__ gp, const float* __restrict__ bep,
    ushort* __restrict__ h0b, ushort* __restrict__ xb, float* __restrict__ fout, int N)
{
    const int lane = threadIdx.x & 63;
    const int wc = threadIdx.x >> 6;
    const int lr = lane & 15;
    const int hi = lane >> 4;
    const int row0 = blockIdx.x*16;
    __shared__ float sm1[16][4];
    __shared__ float sm2[16][4];

    f32x4 acc[4];
    #pragma unroll
    for(int n=0;n<4;n++){ acc[n].x=0.f; acc[n].y=0.f; acc[n].z=0.f; acc[n].w=0.f; }

    int r0 = row0 + lr; if(r0 >= N) r0 = N-1;
    const ushort* ap0 = A + (size_t)r0*256 + hi*8;
    const ushort* bpp = Wb + (wc*64 + lr)*32 + hi*8;

    s16x8 a0[2], bb[2][4];
    a0[0] = *reinterpret_cast<const s16x8*>(ap0);
    #pragma unroll
    for(int nf=0;nf<4;nf++) bb[0][nf] = *reinterpret_cast<const s16x8*>(bpp + nf*512);

    #pragma unroll
    for(int kb=0; kb<8; kb++){
        const int cur = kb&1, nxt = cur^1;
        if(kb < 7){
            a0[nxt] = *reinterpret_cast<const s16x8*>(ap0 + (kb+1)*32);
            #pragma unroll
            for(int nf=0;nf<4;nf++)
                bb[nxt][nf] = *reinterpret_cast<const s16x8*>(bpp + (kb+1)*8192 + nf*512);
        }
        #pragma unroll
        for(int nf=0;nf<4;nf++)
            acc[nf] = __builtin_amdgcn_mfma_f32_16x16x32_bf16(a0[cur], bb[cur][nf], acc[nf], 0,0,0);
    }
    epilogue16<MODE>(acc, bp, gp, bep, h0b, xb, fout, row0, wc, lr, hi, N, sm1, sm2);
}

extern "C" void kernel_launch(void* const* d_in, const int* in_sizes, int n_in,
                              void* d_out, int out_size, void* d_ws, size_t ws_size,
                              hipStream_t stream){
    const float* x     = (const float*)d_in[0];
    const int*   ei    = (const int*)d_in[1];
    const float* W_in  = (const float*)d_in[2];
    const float* b_in  = (const float*)d_in[3];
    const float* g_in  = (const float*)d_in[4];
    const float* be_in = (const float*)d_in[5];
    const float* Wc    = (const float*)d_in[6];
    const float* bc    = (const float*)d_in[7];
    const float* gc    = (const float*)d_in[8];
    const float* bec   = (const float*)d_in[9];
    const int N = in_sizes[0]/128;
    const int E = in_sizes[1]/2;
    const int* src = ei;
    const int* dst = ei + E;
    float* fout = (float*)d_out;
    const int B = (N+1023)/1024;

    char* w = (char*)d_ws;
    ushort* xb   = (ushort*)w; w += (size_t)N*HID*2;
    ushort* yb   = (ushort*)w; w += (size_t)N*HID*2;
    ushort* h0b  = (ushort*)w; w += (size_t)N*HID*2;
    ushort* wbin = (ushort*)w; w += (size_t)128*256*2;
    ushort* wbc  = (ushort*)w; w += (size_t)6*65536*2;
    float* dinv  = (float*)w;  w += (size_t)N*4;
    int* cnt     = (int*)w;    w += (size_t)N*4;
    int* cursor  = (int*)w;    w += (size_t)N*4;
    int* csr     = (int*)w;    w += (size_t)E*4;
    int* indptr  = (int*)w;    w += (size_t)(N+1)*4;
    int* tsum    = (int*)w;    w += (size_t)B*256*4;
    int* bsum    = (int*)w;    w += (size_t)B*4;

    (void)hipMemsetAsync(cnt, 0, (size_t)N*4, stream);
    k_cvt_count<<<CVTB + (E+255)/256,256,0,stream>>>(W_in, Wc, wbin, wbc, dst, cnt, E);
    k_scan1<<<B,256,0,stream>>>(cnt, tsum, bsum, N);
    k_scan3<<<B,256,0,stream>>>(cnt, tsum, bsum, indptr, cursor, dinv, N, B);
    k_fill<<<(E+255)/256,256,0,stream>>>(src,dst,cursor,csr,E);

    const int GB = (N+15)/16;
    k_gemm_in<<<GB,256,0,stream>>>(x, wbin, b_in, g_in, be_in, h0b, xb, N);
    for(int l=0;l<6;l++){
        k_agg<<<(N+3)/4,256,0,stream>>>(xb, indptr, csr, dinv, yb, N);
        if(l<5)
            k_gemm_fused<1><<<GB,256,0,stream>>>(yb, wbc+(size_t)l*65536,
                bc+(size_t)l*HID, gc+(size_t)l*HID, bec+(size_t)l*HID,
                h0b, xb, nullptr, N);
        else
            k_gemm_fused<2><<<GB,256,0,stream>>>(yb, wbc+(size_t)l*65536,
                bc+(size_t)l*HID, gc+(size_t)l*HID, bec+(size_t)l*HID,
                h0b, xb, fout, N);
    }
}